// Round 5
// baseline (79.939 us; speedup 1.0000x reference)
//
#include <hip/hip_runtime.h>

#define BATCH 16
#define NBOX  2048
#define NCLS  80
#define ROWF  85
#define CONF_THRF 0.2f
#define NMS_THRF  0.45f
#define CAP   128      // per-(img,class) candidate cap; Poisson(20.5) tail past 128 ~ 1e-40

// ws layout (bytes)
#define WS_KEPT 0                                  // u64 [16*2048] per-image kept keys
#define WS_S    (WS_KEPT + BATCH*NBOX*8)           // f32 [16*2048] scores
#define WS_CP   (WS_S    + BATCH*NBOX*4)           // f32 [16*2048] classprob max
#define WS_BUCK (WS_CP   + BATCH*NBOX*4)           // u16 [1280*CAP] bucket idx lists
#define WS_CNT  (WS_BUCK + BATCH*NCLS*CAP*2)       // i32 [1280] bucket counts
#define WS_KCNT (WS_CNT  + BATCH*NCLS*4)           // i32 [16] kept counts

static __device__ inline unsigned long long shflx64(unsigned long long v, int m) {
  int lo = __shfl_xor((int)(unsigned)(v & 0xffffffffull), m, 64);
  int hi = __shfl_xor((int)(unsigned)(v >> 32), m, 64);
  return ((unsigned long long)(unsigned)hi << 32) | (unsigned)lo;
}

// ---- kernel 1: argmax/score per row (16 lanes per row) + candidate bucketing + zero out ----
__global__ __launch_bounds__(256) void prep_kernel(const float* __restrict__ det,
                                                   float* __restrict__ s_ws,
                                                   float* __restrict__ cp_ws,
                                                   unsigned short* __restrict__ bucket,
                                                   int* __restrict__ cnt,
                                                   float* __restrict__ outz) {
  const int tid = threadIdx.x;
  const int lane = tid & 63, wavei = tid >> 6;
  const int sub = lane & 15, grp = lane >> 4;
  const int row = blockIdx.x * 16 + wavei * 4 + grp;      // 2048 blocks * 16 rows = 32768

  // zero entire output (1 MB) with first 65536 global threads
  int gid = blockIdx.x * 256 + tid;
  if (gid < (BATCH * NBOX * 8) / 4) ((float4*)outz)[gid] = make_float4(0.f, 0.f, 0.f, 0.f);

  const float* r = det + (size_t)row * ROWF;
  float best = r[5 + sub];
  int bc = sub;
#pragma unroll
  for (int k = 1; k < 5; ++k) {                            // classes sub+16k, k=0..4 (<80)
    float v = r[5 + sub + 16 * k];
    if (v > best) { best = v; bc = sub + 16 * k; }         // strict >: first max wins
  }
#pragma unroll
  for (int d = 1; d < 16; d <<= 1) {                       // 16-lane argmax, tie -> min idx
    float ov = __shfl_xor(best, d, 16);
    int oc = __shfl_xor(bc, d, 16);
    if (ov > best || (ov == best && oc < bc)) { best = ov; bc = oc; }
  }
  if (sub == 0) {
    float sc = r[4];
    s_ws[row] = sc;
    cp_ws[row] = best;
    if (sc > CONF_THRF) {
      int img = row >> 11, n = row & (NBOX - 1);
      int b = img * NCLS + bc;
      int slot = atomicAdd(&cnt[b], 1);
      if (slot < CAP) bucket[b * CAP + slot] = (unsigned short)n;
    }
  }
}

// ---- kernel 2: one wave per (img,class): sort bucket by (score desc, idx asc), greedy NMS ----
__global__ __launch_bounds__(64) void nmsb_kernel(const float* __restrict__ det,
                                                  const float* __restrict__ s_ws,
                                                  const unsigned short* __restrict__ bucket,
                                                  const int* __restrict__ cnt,
                                                  unsigned long long* __restrict__ kept,
                                                  int* __restrict__ kcnt) {
  const int b = blockIdx.x;                 // img*80 + c
  const int img = b / NCLS, c = b - img * NCLS;
  const int lane = threadIdx.x;
  int m = cnt[b];
  if (m > CAP) m = CAP;
  if (m == 0) return;
  const size_t ibase = (size_t)img * NBOX;

  // keys: (~score_bits)<<32 | idx  -> ascending == (score desc, idx asc); pad = all-ones
  unsigned long long e0 = ~0ull, e1 = ~0ull;
  if (lane < m) {
    int n = bucket[b * CAP + lane];
    e0 = ((unsigned long long)(~__float_as_uint(s_ws[ibase + n])) << 32) | (unsigned)n;
  }
  if (lane + 64 < m) {
    int n = bucket[b * CAP + lane + 64];
    e1 = ((unsigned long long)(~__float_as_uint(s_ws[ibase + n])) << 32) | (unsigned)n;
  }

  const bool two = (m > 64);
  if (!two) {
    // 64-element in-register bitonic (21 shfl passes)
#pragma unroll
    for (int k = 2; k <= 64; k <<= 1)
      for (int j = k >> 1; j > 0; j >>= 1) {
        bool amLow = (lane & j) == 0;
        bool up = ((lane & k) == 0);
        unsigned long long o = shflx64(e0, j);
        e0 = (up == amLow) ? (e0 < o ? e0 : o) : (e0 > o ? e0 : o);
      }
  } else {
    // 128-element: i0=lane, i1=lane+64 (R4-proven network)
#pragma unroll
    for (int k = 2; k <= 128; k <<= 1)
      for (int j = k >> 1; j > 0; j >>= 1) {
        if (j == 64) {
          bool up = ((lane & k) == 0);
          if (up ? (e0 > e1) : (e0 < e1)) { unsigned long long t = e0; e0 = e1; e1 = t; }
        } else {
          bool amLow = (lane & j) == 0;
          bool up0 = ((lane & k) == 0), up1 = (((lane + 64) & k) == 0);
          unsigned long long o0 = shflx64(e0, j), o1 = shflx64(e1, j);
          e0 = (up0 == amLow) ? (e0 < o0 ? e0 : o0) : (e0 > o0 ? e0 : o0);
          e1 = (up1 == amLow) ? (e1 < o1 ? e1 : o1) : (e1 > o1 ? e1 : o1);
        }
      }
  }

  // decode offset boxes (f32 x+lab*10000, exact ref rounding) for sorted elems
  const float off = (float)c * 10000.0f;
  bool valid0 = lane < m, valid1 = two && (lane + 64 < m);
  int n0 = (int)((unsigned)e0 & (NBOX - 1));
  int n1 = (int)((unsigned)e1 & (NBOX - 1));
  float x1 = 0, y1 = 0, x2 = 0, y2 = 0, ar = 0;
  if (valid0) {
    const float* rr = det + (ibase + n0) * ROWF;
    x1 = rr[0] + off; y1 = rr[1] + off; x2 = rr[2] + off; y2 = rr[3] + off;
    ar = fmaxf(x2 - x1, 0.0f) * fmaxf(y2 - y1, 0.0f);
  }
  float X1 = 0, Y1 = 0, X2 = 0, Y2 = 0, AR = 0;
  if (valid1) {
    const float* rr = det + (ibase + n1) * ROWF;
    X1 = rr[0] + off; Y1 = rr[1] + off; X2 = rr[2] + off; Y2 = rr[3] + off;
    AR = fmaxf(X2 - X1, 0.0f) * fmaxf(Y2 - Y1, 0.0f);
  }

  // ballot-greedy on chunk0
  unsigned long long keptm0 = 0, und = __ballot(valid0);
  while (und) {
    int i = __ffsll((long long)und) - 1;
    keptm0 |= 1ull << i;
    float kx1 = __shfl(x1, i, 64), ky1 = __shfl(y1, i, 64);
    float kx2 = __shfl(x2, i, 64), ky2 = __shfl(y2, i, 64);
    float kar = __shfl(ar, i, 64);
    float iw = fminf(x2, kx2) - fmaxf(x1, kx1);
    float ih = fminf(y2, ky2) - fmaxf(y1, ky1);
    float inter = fmaxf(iw, 0.0f) * fmaxf(ih, 0.0f);
    float iou = inter / (((kar + ar) - inter) + 1e-7f);     // exact ref op order
    bool sup = (lane > i) && (iou > NMS_THRF);
    und &= ~__ballot(sup);
    und &= ~(1ull << i);
  }
  // chunk1: suppress vs chunk0 kept, then greedy
  unsigned long long keptm1 = 0;
  if (two) {
    bool dead = false;
    unsigned long long km = keptm0;
    while (km) {
      int t = __ffsll((long long)km) - 1; km &= km - 1;
      float kx1 = __shfl(x1, t, 64), ky1 = __shfl(y1, t, 64);
      float kx2 = __shfl(x2, t, 64), ky2 = __shfl(y2, t, 64);
      float kar = __shfl(ar, t, 64);
      float iw = fminf(X2, kx2) - fmaxf(X1, kx1);
      float ih = fminf(Y2, ky2) - fmaxf(Y1, ky1);
      float inter = fmaxf(iw, 0.0f) * fmaxf(ih, 0.0f);
      float iou = inter / (((kar + AR) - inter) + 1e-7f);
      dead |= (iou > NMS_THRF);
    }
    unsigned long long und1 = __ballot(valid1 && !dead);
    while (und1) {
      int i = __ffsll((long long)und1) - 1;
      keptm1 |= 1ull << i;
      float kx1 = __shfl(X1, i, 64), ky1 = __shfl(Y1, i, 64);
      float kx2 = __shfl(X2, i, 64), ky2 = __shfl(Y2, i, 64);
      float kar = __shfl(AR, i, 64);
      float iw = fminf(X2, kx2) - fmaxf(X1, kx1);
      float ih = fminf(Y2, ky2) - fmaxf(Y1, ky1);
      float inter = fmaxf(iw, 0.0f) * fmaxf(ih, 0.0f);
      float iou = inter / (((kar + AR) - inter) + 1e-7f);
      bool sup = (lane > i) && (iou > NMS_THRF);
      und1 &= ~__ballot(sup);
      und1 &= ~(1ull << i);
    }
  }

  // append kept keys (global-order key: (~score)<<32 | idx<<7 | label) to per-image list
  int nk = __popcll(keptm0) + __popcll(keptm1);
  int base = 0;
  if (lane == 0 && nk) base = atomicAdd(&kcnt[img], nk);
  base = __shfl(base, 0, 64);
  if ((keptm0 >> lane) & 1) {
    int rank = __popcll(keptm0 & ((1ull << lane) - 1ull));
    kept[ibase + base + rank] = (e0 & 0xffffffff00000000ull) | (unsigned)((n0 << 7) | c);
  }
  if (two && ((keptm1 >> lane) & 1)) {
    int rank = __popcll(keptm0) + __popcll(keptm1 & ((1ull << lane) - 1ull));
    kept[ibase + base + rank] = (e1 & 0xffffffff00000000ull) | (unsigned)((n1 << 7) | c);
  }
}

// ---- kernel 3: rank-by-count (no sort) + scatter-write kept rows; tail stays zero ----
__global__ __launch_bounds__(512) void outc_kernel(const float* __restrict__ det,
                                                   const float* __restrict__ cp_ws,
                                                   const unsigned long long* __restrict__ kept,
                                                   const int* __restrict__ kcnt,
                                                   float* __restrict__ out) {
  __shared__ unsigned long long keys[NBOX];
  const int img = blockIdx.x >> 2, sub = blockIdx.x & 3;
  const int tid = threadIdx.x;
  const int K = kcnt[img];
  const size_t ibase = (size_t)img * NBOX;
  for (int t = tid; t < NBOX; t += 512)
    keys[t] = (t < K) ? kept[ibase + t] : ~0ull;
  __syncthreads();
  int j = sub * 512 + tid;
  if (j >= K) return;
  unsigned long long my = keys[j];
  int rank = 0;
#pragma unroll 4
  for (int t = 0; t < K; ++t) rank += (keys[t] < my) ? 1 : 0;   // keys unique -> exact rank
  unsigned meta = (unsigned)my;
  int idx = (meta >> 7) & (NBOX - 1);
  int lb = meta & 127;
  const float* rr = det + (ibase + idx) * ROWF;                 // original boxes
  float sc = __uint_as_float(~(unsigned)(my >> 32));
  float* orow = out + (ibase + rank) * 6;
  orow[0] = rr[0]; orow[1] = rr[1]; orow[2] = rr[2]; orow[3] = rr[3];
  orow[4] = sc; orow[5] = cp_ws[ibase + idx];
  out[(size_t)BATCH * NBOX * 6 + ibase + rank] = (float)lb;
  out[(size_t)BATCH * NBOX * 7 + ibase + rank] = 1.0f;
}

extern "C" void kernel_launch(void* const* d_in, const int* in_sizes, int n_in,
                              void* d_out, int out_size, void* d_ws, size_t ws_size,
                              hipStream_t stream) {
  const float* det = (const float*)d_in[0];
  float* out = (float*)d_out;
  char* ws = (char*)d_ws;

  unsigned long long* keptb = (unsigned long long*)(ws + WS_KEPT);
  float* s_ws = (float*)(ws + WS_S);
  float* cp_ws = (float*)(ws + WS_CP);
  unsigned short* bucket = (unsigned short*)(ws + WS_BUCK);
  int* cnt = (int*)(ws + WS_CNT);
  int* kcnt = (int*)(ws + WS_KCNT);

  hipMemsetAsync(ws + WS_CNT, 0, (BATCH * NCLS + BATCH) * 4, stream);
  prep_kernel<<<BATCH * NBOX / 16, 256, 0, stream>>>(det, s_ws, cp_ws, bucket, cnt, out);
  nmsb_kernel<<<BATCH * NCLS, 64, 0, stream>>>(det, s_ws, bucket, cnt, keptb, kcnt);
  outc_kernel<<<BATCH * 4, 512, 0, stream>>>(det, cp_ws, keptb, kcnt, out);
}

// Round 6
// 58.851 us; speedup vs baseline: 1.3583x; 1.3583x over previous
//
#include <hip/hip_runtime.h>

#define BATCH 16
#define NBOX  2048
#define NCLS  80
#define ROWF  85
#define CONF_THRF 0.2f
#define NMS_THRF  0.45f
#define CAP   128      // per-(img,class) candidate cap; Poisson(20.5) tail past 128 ~ 1e-40

// ws layout (bytes)
#define WS_KEPT 0                                  // u64 [16*2048] per-image kept keys
#define WS_S    (WS_KEPT + BATCH*NBOX*8)           // f32 [16*2048] scores
#define WS_CP   (WS_S    + BATCH*NBOX*4)           // f32 [16*2048] classprob max
#define WS_BUCK (WS_CP   + BATCH*NBOX*4)           // u16 [1280*CAP] bucket idx lists
#define WS_CNT  (WS_BUCK + BATCH*NCLS*CAP*2)       // i32 [1280] bucket counts
#define WS_KCNT (WS_CNT  + BATCH*NCLS*4)           // i32 [16] kept counts

static __device__ inline unsigned long long shflx64(unsigned long long v, int m) {
  int lo = __shfl_xor((int)(unsigned)(v & 0xffffffffull), m, 64);
  int hi = __shfl_xor((int)(unsigned)(v >> 32), m, 64);
  return ((unsigned long long)(unsigned)hi << 32) | (unsigned)lo;
}

// ---- kernel 1: argmax/score per row (16 lanes per row) + candidate bucketing + zero out ----
__global__ __launch_bounds__(256) void prep_kernel(const float* __restrict__ det,
                                                   float* __restrict__ s_ws,
                                                   float* __restrict__ cp_ws,
                                                   unsigned short* __restrict__ bucket,
                                                   int* __restrict__ cnt,
                                                   float* __restrict__ outz) {
  const int tid = threadIdx.x;
  const int lane = tid & 63, wavei = tid >> 6;
  const int sub = lane & 15, grp = lane >> 4;
  const int row = blockIdx.x * 16 + wavei * 4 + grp;      // 2048 blocks * 16 rows = 32768

  // zero entire output (1 MB) with first 65536 global threads
  int gid = blockIdx.x * 256 + tid;
  if (gid < (BATCH * NBOX * 8) / 4) ((float4*)outz)[gid] = make_float4(0.f, 0.f, 0.f, 0.f);

  const float* r = det + (size_t)row * ROWF;
  float best = r[5 + sub];
  int bc = sub;
#pragma unroll
  for (int k = 1; k < 5; ++k) {                            // classes sub+16k, k=0..4 (<80)
    float v = r[5 + sub + 16 * k];
    if (v > best) { best = v; bc = sub + 16 * k; }         // strict >: first max wins
  }
#pragma unroll
  for (int d = 1; d < 16; d <<= 1) {                       // 16-lane argmax, tie -> min idx
    float ov = __shfl_xor(best, d, 16);
    int oc = __shfl_xor(bc, d, 16);
    if (ov > best || (ov == best && oc < bc)) { best = ov; bc = oc; }
  }
  if (sub == 0) {
    float sc = r[4];
    s_ws[row] = sc;
    cp_ws[row] = best;
    if (sc > CONF_THRF) {
      int img = row >> 11, n = row & (NBOX - 1);
      int b = img * NCLS + bc;
      int slot = atomicAdd(&cnt[b], 1);
      if (slot < CAP) bucket[b * CAP + slot] = (unsigned short)n;
    }
  }
}

// ---- kernel 2: one wave per (img,class): sort bucket by (score desc, idx asc), greedy NMS ----
__global__ __launch_bounds__(64) void nmsb_kernel(const float* __restrict__ det,
                                                  const float* __restrict__ s_ws,
                                                  const unsigned short* __restrict__ bucket,
                                                  const int* __restrict__ cnt,
                                                  unsigned long long* __restrict__ kept,
                                                  int* __restrict__ kcnt) {
  const int b = blockIdx.x;                 // img*80 + c
  const int img = b / NCLS, c = b - img * NCLS;
  const int lane = threadIdx.x;
  int m = cnt[b];
  if (m > CAP) m = CAP;
  if (m == 0) return;
  const size_t ibase = (size_t)img * NBOX;

  // keys: (~score_bits)<<32 | idx  -> ascending == (score desc, idx asc); pad = all-ones
  unsigned long long e0 = ~0ull, e1 = ~0ull;
  if (lane < m) {
    int n = bucket[b * CAP + lane];
    e0 = ((unsigned long long)(~__float_as_uint(s_ws[ibase + n])) << 32) | (unsigned)n;
  }
  if (lane + 64 < m) {
    int n = bucket[b * CAP + lane + 64];
    e1 = ((unsigned long long)(~__float_as_uint(s_ws[ibase + n])) << 32) | (unsigned)n;
  }

  const bool two = (m > 64);
  if (!two) {
#pragma unroll
    for (int k = 2; k <= 64; k <<= 1)
      for (int j = k >> 1; j > 0; j >>= 1) {
        bool amLow = (lane & j) == 0;
        bool up = ((lane & k) == 0);
        unsigned long long o = shflx64(e0, j);
        e0 = (up == amLow) ? (e0 < o ? e0 : o) : (e0 > o ? e0 : o);
      }
  } else {
#pragma unroll
    for (int k = 2; k <= 128; k <<= 1)
      for (int j = k >> 1; j > 0; j >>= 1) {
        if (j == 64) {
          bool up = ((lane & k) == 0);
          if (up ? (e0 > e1) : (e0 < e1)) { unsigned long long t = e0; e0 = e1; e1 = t; }
        } else {
          bool amLow = (lane & j) == 0;
          bool up0 = ((lane & k) == 0), up1 = (((lane + 64) & k) == 0);
          unsigned long long o0 = shflx64(e0, j), o1 = shflx64(e1, j);
          e0 = (up0 == amLow) ? (e0 < o0 ? e0 : o0) : (e0 > o0 ? e0 : o0);
          e1 = (up1 == amLow) ? (e1 < o1 ? e1 : o1) : (e1 > o1 ? e1 : o1);
        }
      }
  }

  // decode offset boxes (f32 x+lab*10000, exact ref rounding) for sorted elems
  const float off = (float)c * 10000.0f;
  bool valid0 = lane < m, valid1 = two && (lane + 64 < m);
  int n0 = (int)((unsigned)e0 & (NBOX - 1));
  int n1 = (int)((unsigned)e1 & (NBOX - 1));
  float x1 = 0, y1 = 0, x2 = 0, y2 = 0, ar = 0;
  if (valid0) {
    const float* rr = det + (ibase + n0) * ROWF;
    x1 = rr[0] + off; y1 = rr[1] + off; x2 = rr[2] + off; y2 = rr[3] + off;
    ar = fmaxf(x2 - x1, 0.0f) * fmaxf(y2 - y1, 0.0f);
  }
  float X1 = 0, Y1 = 0, X2 = 0, Y2 = 0, AR = 0;
  if (valid1) {
    const float* rr = det + (ibase + n1) * ROWF;
    X1 = rr[0] + off; Y1 = rr[1] + off; X2 = rr[2] + off; Y2 = rr[3] + off;
    AR = fmaxf(X2 - X1, 0.0f) * fmaxf(Y2 - Y1, 0.0f);
  }

  // ballot-greedy on chunk0
  unsigned long long keptm0 = 0, und = __ballot(valid0);
  while (und) {
    int i = __ffsll((long long)und) - 1;
    keptm0 |= 1ull << i;
    float kx1 = __shfl(x1, i, 64), ky1 = __shfl(y1, i, 64);
    float kx2 = __shfl(x2, i, 64), ky2 = __shfl(y2, i, 64);
    float kar = __shfl(ar, i, 64);
    float iw = fminf(x2, kx2) - fmaxf(x1, kx1);
    float ih = fminf(y2, ky2) - fmaxf(y1, ky1);
    float inter = fmaxf(iw, 0.0f) * fmaxf(ih, 0.0f);
    float iou = inter / (((kar + ar) - inter) + 1e-7f);     // exact ref op order
    bool sup = (lane > i) && (iou > NMS_THRF);
    und &= ~__ballot(sup);
    und &= ~(1ull << i);
  }
  // chunk1: suppress vs chunk0 kept, then greedy
  unsigned long long keptm1 = 0;
  if (two) {
    bool dead = false;
    unsigned long long km = keptm0;
    while (km) {
      int t = __ffsll((long long)km) - 1; km &= km - 1;
      float kx1 = __shfl(x1, t, 64), ky1 = __shfl(y1, t, 64);
      float kx2 = __shfl(x2, t, 64), ky2 = __shfl(y2, t, 64);
      float kar = __shfl(ar, t, 64);
      float iw = fminf(X2, kx2) - fmaxf(X1, kx1);
      float ih = fminf(Y2, ky2) - fmaxf(Y1, ky1);
      float inter = fmaxf(iw, 0.0f) * fmaxf(ih, 0.0f);
      float iou = inter / (((kar + AR) - inter) + 1e-7f);
      dead |= (iou > NMS_THRF);
    }
    unsigned long long und1 = __ballot(valid1 && !dead);
    while (und1) {
      int i = __ffsll((long long)und1) - 1;
      keptm1 |= 1ull << i;
      float kx1 = __shfl(X1, i, 64), ky1 = __shfl(Y1, i, 64);
      float kx2 = __shfl(X2, i, 64), ky2 = __shfl(Y2, i, 64);
      float kar = __shfl(AR, i, 64);
      float iw = fminf(X2, kx2) - fmaxf(X1, kx1);
      float ih = fminf(Y2, ky2) - fmaxf(Y1, ky1);
      float inter = fmaxf(iw, 0.0f) * fmaxf(ih, 0.0f);
      float iou = inter / (((kar + AR) - inter) + 1e-7f);
      bool sup = (lane > i) && (iou > NMS_THRF);
      und1 &= ~__ballot(sup);
      und1 &= ~(1ull << i);
    }
  }

  // append kept keys (global-order key: (~score)<<32 | idx<<7 | label) to per-image list
  int nk = __popcll(keptm0) + __popcll(keptm1);
  int base = 0;
  if (lane == 0 && nk) base = atomicAdd(&kcnt[img], nk);
  base = __shfl(base, 0, 64);
  if ((keptm0 >> lane) & 1) {
    int rank = __popcll(keptm0 & ((1ull << lane) - 1ull));
    kept[ibase + base + rank] = (e0 & 0xffffffff00000000ull) | (unsigned)((n0 << 7) | c);
  }
  if (two && ((keptm1 >> lane) & 1)) {
    int rank = __popcll(keptm0) + __popcll(keptm1 & ((1ull << lane) - 1ull));
    kept[ibase + base + rank] = (e1 & 0xffffffff00000000ull) | (unsigned)((n1 << 7) | c);
  }
}

// ---- kernel 3: per-image hybrid reg/LDS bitonic sort of kept keys + direct row writes ----
__global__ __launch_bounds__(1024) void outs_kernel(const float* __restrict__ det,
                                                    const float* __restrict__ cp_ws,
                                                    const unsigned long long* __restrict__ kept,
                                                    const int* __restrict__ kcnt,
                                                    float* __restrict__ out) {
  __shared__ unsigned long long key[NBOX];                 // 16 KB sort scratch
  const int img = blockIdx.x;
  const int tid = threadIdx.x;
  const int lane = tid & 63, wid = tid >> 6;
  const size_t ibase = (size_t)img * NBOX;
  const int K = kcnt[img];
  const int i0 = (wid << 7) + lane, i1 = i0 + 64;

  unsigned long long e0 = (i0 < K) ? kept[ibase + i0] : ~0ull;
  unsigned long long e1 = (i1 < K) ? kept[ibase + i1] : ~0ull;

  // stages k=2..128: fully in-register (R4-proven network)
#pragma unroll
  for (int k = 2; k <= 128; k <<= 1) {
    for (int j = k >> 1; j > 0; j >>= 1) {
      if (j == 64) {
        bool up = ((i0 & k) == 0);
        if (up ? (e0 > e1) : (e0 < e1)) { unsigned long long t = e0; e0 = e1; e1 = t; }
      } else {
        bool amLow = (lane & j) == 0;
        bool up0 = ((i0 & k) == 0), up1 = ((i1 & k) == 0);
        unsigned long long o0 = shflx64(e0, j), o1 = shflx64(e1, j);
        e0 = (up0 == amLow) ? (e0 < o0 ? e0 : o0) : (e0 > o0 ? e0 : o0);
        e1 = (up1 == amLow) ? (e1 < o1 ? e1 : o1) : (e1 > o1 ? e1 : o1);
      }
    }
  }
  // stages k=256..2048: j>=128 via LDS, j<=64 back in registers
  for (int k = 256; k <= NBOX; k <<= 1) {
    key[i0] = e0; key[i1] = e1;
    __syncthreads();
    for (int j = k >> 1; j >= 128; j >>= 1) {
      int i = ((tid & ~(j - 1)) << 1) | (tid & (j - 1));
      int ixj = i + j;
      unsigned long long a = key[i], b = key[ixj];
      bool up = ((i & k) == 0);
      if (up ? (a > b) : (a < b)) { key[i] = b; key[ixj] = a; }
      __syncthreads();
    }
    e0 = key[i0]; e1 = key[i1];
#pragma unroll
    for (int j = 64; j > 0; j >>= 1) {
      if (j == 64) {
        bool up = ((i0 & k) == 0);
        if (up ? (e0 > e1) : (e0 < e1)) { unsigned long long t = e0; e0 = e1; e1 = t; }
      } else {
        bool amLow = (lane & j) == 0;
        bool up0 = ((i0 & k) == 0), up1 = ((i1 & k) == 0);
        unsigned long long o0 = shflx64(e0, j), o1 = shflx64(e1, j);
        e0 = (up0 == amLow) ? (e0 < o0 ? e0 : o0) : (e0 > o0 ? e0 : o0);
        e1 = (up1 == amLow) ? (e1 < o1 ? e1 : o1) : (e1 > o1 ? e1 : o1);
      }
    }
  }

  // write rows for sorted ranks i0, i1 (tail rows stay zero from prep)
#pragma unroll
  for (int s = 0; s < 2; ++s) {
    int r = s ? i1 : i0;
    unsigned long long kv = s ? e1 : e0;
    if (r < K) {
      unsigned meta = (unsigned)kv;
      int idx = (meta >> 7) & (NBOX - 1);
      int lb = meta & 127;
      const float* rr = det + (ibase + idx) * ROWF;        // original (non-offset) boxes
      float* orow = out + (ibase + r) * 6;
      orow[0] = rr[0]; orow[1] = rr[1]; orow[2] = rr[2]; orow[3] = rr[3];
      orow[4] = __uint_as_float(~(unsigned)(kv >> 32));
      orow[5] = cp_ws[ibase + idx];
      out[(size_t)BATCH * NBOX * 6 + ibase + r] = (float)lb;
      out[(size_t)BATCH * NBOX * 7 + ibase + r] = 1.0f;
    }
  }
}

extern "C" void kernel_launch(void* const* d_in, const int* in_sizes, int n_in,
                              void* d_out, int out_size, void* d_ws, size_t ws_size,
                              hipStream_t stream) {
  const float* det = (const float*)d_in[0];
  float* out = (float*)d_out;
  char* ws = (char*)d_ws;

  unsigned long long* keptb = (unsigned long long*)(ws + WS_KEPT);
  float* s_ws = (float*)(ws + WS_S);
  float* cp_ws = (float*)(ws + WS_CP);
  unsigned short* bucket = (unsigned short*)(ws + WS_BUCK);
  int* cnt = (int*)(ws + WS_CNT);
  int* kcnt = (int*)(ws + WS_KCNT);

  hipMemsetAsync(ws + WS_CNT, 0, (BATCH * NCLS + BATCH) * 4, stream);
  prep_kernel<<<BATCH * NBOX / 16, 256, 0, stream>>>(det, s_ws, cp_ws, bucket, cnt, out);
  nmsb_kernel<<<BATCH * NCLS, 64, 0, stream>>>(det, s_ws, bucket, cnt, keptb, kcnt);
  outs_kernel<<<BATCH, 1024, 0, stream>>>(det, cp_ws, keptb, kcnt, out);
}

// Round 7
// 58.693 us; speedup vs baseline: 1.3620x; 1.0027x over previous
//
#include <hip/hip_runtime.h>

#define BATCH 16
#define NBOX  2048
#define NCLS  80
#define ROWF  85
#define CONF_THRF 0.2f
#define NMS_THRF  0.45f
#define CAP   128      // per-(img,class) candidate cap; Poisson(20.5) tail past 128 ~ 1e-40

// ws layout (bytes)
#define WS_KEPT 0                                  // u64 [16*2048] per-image kept keys
#define WS_S    (WS_KEPT + BATCH*NBOX*8)           // f32 [16*2048] scores
#define WS_CP   (WS_S    + BATCH*NBOX*4)           // f32 [16*2048] classprob max
#define WS_BUCK (WS_CP   + BATCH*NBOX*4)           // u16 [1280*CAP] bucket idx lists
#define WS_CNT  (WS_BUCK + BATCH*NCLS*CAP*2)       // i32 [1280] bucket counts
#define WS_KCNT (WS_CNT  + BATCH*NCLS*4)           // i32 [16] kept counts
#define NCTR    (BATCH*NCLS + BATCH)               // ints to zero each call

static __device__ inline unsigned long long shflx64(unsigned long long v, int m) {
  int lo = __shfl_xor((int)(unsigned)(v & 0xffffffffull), m, 64);
  int hi = __shfl_xor((int)(unsigned)(v >> 32), m, 64);
  return ((unsigned long long)(unsigned)hi << 32) | (unsigned)lo;
}

// ---- kernel 0: zero the atomic counters (replaces 40us rocclr fillBuffer) ----
__global__ __launch_bounds__(512) void zclr_kernel(int* __restrict__ ctr) {
  int t = threadIdx.x;
#pragma unroll
  for (int i = t; i < NCTR; i += 512) ctr[i] = 0;
}

// ---- kernel 1: argmax/score per row (16 lanes per row) + candidate bucketing + zero out ----
__global__ __launch_bounds__(256) void prep_kernel(const float* __restrict__ det,
                                                   float* __restrict__ s_ws,
                                                   float* __restrict__ cp_ws,
                                                   unsigned short* __restrict__ bucket,
                                                   int* __restrict__ cnt,
                                                   float* __restrict__ outz) {
  const int tid = threadIdx.x;
  const int lane = tid & 63, wavei = tid >> 6;
  const int sub = lane & 15, grp = lane >> 4;
  const int row = blockIdx.x * 16 + wavei * 4 + grp;      // 2048 blocks * 16 rows = 32768

  // zero entire output (1 MB) with first 65536 global threads
  int gid = blockIdx.x * 256 + tid;
  if (gid < (BATCH * NBOX * 8) / 4) ((float4*)outz)[gid] = make_float4(0.f, 0.f, 0.f, 0.f);

  const float* r = det + (size_t)row * ROWF;
  float best = r[5 + sub];
  int bc = sub;
#pragma unroll
  for (int k = 1; k < 5; ++k) {                            // classes sub+16k, k=0..4 (<80)
    float v = r[5 + sub + 16 * k];
    if (v > best) { best = v; bc = sub + 16 * k; }         // strict >: first max wins
  }
#pragma unroll
  for (int d = 1; d < 16; d <<= 1) {                       // 16-lane argmax, tie -> min idx
    float ov = __shfl_xor(best, d, 16);
    int oc = __shfl_xor(bc, d, 16);
    if (ov > best || (ov == best && oc < bc)) { best = ov; bc = oc; }
  }
  if (sub == 0) {
    float sc = r[4];
    s_ws[row] = sc;
    cp_ws[row] = best;
    if (sc > CONF_THRF) {
      int img = row >> 11, n = row & (NBOX - 1);
      int b = img * NCLS + bc;
      int slot = atomicAdd(&cnt[b], 1);
      if (slot < CAP) bucket[b * CAP + slot] = (unsigned short)n;
    }
  }
}

// ---- kernel 2: one wave per (img,class): sort bucket by (score desc, idx asc), greedy NMS ----
__global__ __launch_bounds__(64) void nmsb_kernel(const float* __restrict__ det,
                                                  const float* __restrict__ s_ws,
                                                  const unsigned short* __restrict__ bucket,
                                                  const int* __restrict__ cnt,
                                                  unsigned long long* __restrict__ kept,
                                                  int* __restrict__ kcnt) {
  const int b = blockIdx.x;                 // img*80 + c
  const int img = b / NCLS, c = b - img * NCLS;
  const int lane = threadIdx.x;
  int m = cnt[b];
  if (m > CAP) m = CAP;
  if (m == 0) return;
  const size_t ibase = (size_t)img * NBOX;

  // keys: (~score_bits)<<32 | idx  -> ascending == (score desc, idx asc); pad = all-ones
  unsigned long long e0 = ~0ull, e1 = ~0ull;
  if (lane < m) {
    int n = bucket[b * CAP + lane];
    e0 = ((unsigned long long)(~__float_as_uint(s_ws[ibase + n])) << 32) | (unsigned)n;
  }
  if (lane + 64 < m) {
    int n = bucket[b * CAP + lane + 64];
    e1 = ((unsigned long long)(~__float_as_uint(s_ws[ibase + n])) << 32) | (unsigned)n;
  }

  const bool two = (m > 64);
  if (!two) {
#pragma unroll
    for (int k = 2; k <= 64; k <<= 1)
      for (int j = k >> 1; j > 0; j >>= 1) {
        bool amLow = (lane & j) == 0;
        bool up = ((lane & k) == 0);
        unsigned long long o = shflx64(e0, j);
        e0 = (up == amLow) ? (e0 < o ? e0 : o) : (e0 > o ? e0 : o);
      }
  } else {
#pragma unroll
    for (int k = 2; k <= 128; k <<= 1)
      for (int j = k >> 1; j > 0; j >>= 1) {
        if (j == 64) {
          bool up = ((lane & k) == 0);
          if (up ? (e0 > e1) : (e0 < e1)) { unsigned long long t = e0; e0 = e1; e1 = t; }
        } else {
          bool amLow = (lane & j) == 0;
          bool up0 = ((lane & k) == 0), up1 = (((lane + 64) & k) == 0);
          unsigned long long o0 = shflx64(e0, j), o1 = shflx64(e1, j);
          e0 = (up0 == amLow) ? (e0 < o0 ? e0 : o0) : (e0 > o0 ? e0 : o0);
          e1 = (up1 == amLow) ? (e1 < o1 ? e1 : o1) : (e1 > o1 ? e1 : o1);
        }
      }
  }

  // decode offset boxes (f32 x+lab*10000, exact ref rounding) for sorted elems
  const float off = (float)c * 10000.0f;
  bool valid0 = lane < m, valid1 = two && (lane + 64 < m);
  int n0 = (int)((unsigned)e0 & (NBOX - 1));
  int n1 = (int)((unsigned)e1 & (NBOX - 1));
  float x1 = 0, y1 = 0, x2 = 0, y2 = 0, ar = 0;
  if (valid0) {
    const float* rr = det + (ibase + n0) * ROWF;
    x1 = rr[0] + off; y1 = rr[1] + off; x2 = rr[2] + off; y2 = rr[3] + off;
    ar = fmaxf(x2 - x1, 0.0f) * fmaxf(y2 - y1, 0.0f);
  }
  float X1 = 0, Y1 = 0, X2 = 0, Y2 = 0, AR = 0;
  if (valid1) {
    const float* rr = det + (ibase + n1) * ROWF;
    X1 = rr[0] + off; Y1 = rr[1] + off; X2 = rr[2] + off; Y2 = rr[3] + off;
    AR = fmaxf(X2 - X1, 0.0f) * fmaxf(Y2 - Y1, 0.0f);
  }

  // ballot-greedy on chunk0
  unsigned long long keptm0 = 0, und = __ballot(valid0);
  while (und) {
    int i = __ffsll((long long)und) - 1;
    keptm0 |= 1ull << i;
    float kx1 = __shfl(x1, i, 64), ky1 = __shfl(y1, i, 64);
    float kx2 = __shfl(x2, i, 64), ky2 = __shfl(y2, i, 64);
    float kar = __shfl(ar, i, 64);
    float iw = fminf(x2, kx2) - fmaxf(x1, kx1);
    float ih = fminf(y2, ky2) - fmaxf(y1, ky1);
    float inter = fmaxf(iw, 0.0f) * fmaxf(ih, 0.0f);
    float iou = inter / (((kar + ar) - inter) + 1e-7f);     // exact ref op order
    bool sup = (lane > i) && (iou > NMS_THRF);
    und &= ~__ballot(sup);
    und &= ~(1ull << i);
  }
  // chunk1: suppress vs chunk0 kept, then greedy
  unsigned long long keptm1 = 0;
  if (two) {
    bool dead = false;
    unsigned long long km = keptm0;
    while (km) {
      int t = __ffsll((long long)km) - 1; km &= km - 1;
      float kx1 = __shfl(x1, t, 64), ky1 = __shfl(y1, t, 64);
      float kx2 = __shfl(x2, t, 64), ky2 = __shfl(y2, t, 64);
      float kar = __shfl(ar, t, 64);
      float iw = fminf(X2, kx2) - fmaxf(X1, kx1);
      float ih = fminf(Y2, ky2) - fmaxf(Y1, ky1);
      float inter = fmaxf(iw, 0.0f) * fmaxf(ih, 0.0f);
      float iou = inter / (((kar + AR) - inter) + 1e-7f);
      dead |= (iou > NMS_THRF);
    }
    unsigned long long und1 = __ballot(valid1 && !dead);
    while (und1) {
      int i = __ffsll((long long)und1) - 1;
      keptm1 |= 1ull << i;
      float kx1 = __shfl(X1, i, 64), ky1 = __shfl(Y1, i, 64);
      float kx2 = __shfl(X2, i, 64), ky2 = __shfl(Y2, i, 64);
      float kar = __shfl(AR, i, 64);
      float iw = fminf(X2, kx2) - fmaxf(X1, kx1);
      float ih = fminf(Y2, ky2) - fmaxf(Y1, ky1);
      float inter = fmaxf(iw, 0.0f) * fmaxf(ih, 0.0f);
      float iou = inter / (((kar + AR) - inter) + 1e-7f);
      bool sup = (lane > i) && (iou > NMS_THRF);
      und1 &= ~__ballot(sup);
      und1 &= ~(1ull << i);
    }
  }

  // append kept keys (global-order key: (~score)<<32 | idx<<7 | label) to per-image list
  int nk = __popcll(keptm0) + __popcll(keptm1);
  int base = 0;
  if (lane == 0 && nk) base = atomicAdd(&kcnt[img], nk);
  base = __shfl(base, 0, 64);
  if ((keptm0 >> lane) & 1) {
    int rank = __popcll(keptm0 & ((1ull << lane) - 1ull));
    kept[ibase + base + rank] = (e0 & 0xffffffff00000000ull) | (unsigned)((n0 << 7) | c);
  }
  if (two && ((keptm1 >> lane) & 1)) {
    int rank = __popcll(keptm0) + __popcll(keptm1 & ((1ull << lane) - 1ull));
    kept[ibase + base + rank] = (e1 & 0xffffffff00000000ull) | (unsigned)((n1 << 7) | c);
  }
}

// ---- kernel 3: per-image hybrid reg/LDS bitonic sort of kept keys + direct row writes ----
__global__ __launch_bounds__(1024) void outs_kernel(const float* __restrict__ det,
                                                    const float* __restrict__ cp_ws,
                                                    const unsigned long long* __restrict__ kept,
                                                    const int* __restrict__ kcnt,
                                                    float* __restrict__ out) {
  __shared__ unsigned long long key[NBOX];                 // 16 KB sort scratch
  const int img = blockIdx.x;
  const int tid = threadIdx.x;
  const int lane = tid & 63, wid = tid >> 6;
  const size_t ibase = (size_t)img * NBOX;
  const int K = kcnt[img];
  const int i0 = (wid << 7) + lane, i1 = i0 + 64;

  unsigned long long e0 = (i0 < K) ? kept[ibase + i0] : ~0ull;
  unsigned long long e1 = (i1 < K) ? kept[ibase + i1] : ~0ull;

  // stages k=2..128: fully in-register (R4-proven network)
#pragma unroll
  for (int k = 2; k <= 128; k <<= 1) {
    for (int j = k >> 1; j > 0; j >>= 1) {
      if (j == 64) {
        bool up = ((i0 & k) == 0);
        if (up ? (e0 > e1) : (e0 < e1)) { unsigned long long t = e0; e0 = e1; e1 = t; }
      } else {
        bool amLow = (lane & j) == 0;
        bool up0 = ((i0 & k) == 0), up1 = ((i1 & k) == 0);
        unsigned long long o0 = shflx64(e0, j), o1 = shflx64(e1, j);
        e0 = (up0 == amLow) ? (e0 < o0 ? e0 : o0) : (e0 > o0 ? e0 : o0);
        e1 = (up1 == amLow) ? (e1 < o1 ? e1 : o1) : (e1 > o1 ? e1 : o1);
      }
    }
  }
  // stages k=256..2048: j>=128 via LDS, j<=64 back in registers
  for (int k = 256; k <= NBOX; k <<= 1) {
    key[i0] = e0; key[i1] = e1;
    __syncthreads();
    for (int j = k >> 1; j >= 128; j >>= 1) {
      int i = ((tid & ~(j - 1)) << 1) | (tid & (j - 1));
      int ixj = i + j;
      unsigned long long a = key[i], b = key[ixj];
      bool up = ((i & k) == 0);
      if (up ? (a > b) : (a < b)) { key[i] = b; key[ixj] = a; }
      __syncthreads();
    }
    e0 = key[i0]; e1 = key[i1];
#pragma unroll
    for (int j = 64; j > 0; j >>= 1) {
      if (j == 64) {
        bool up = ((i0 & k) == 0);
        if (up ? (e0 > e1) : (e0 < e1)) { unsigned long long t = e0; e0 = e1; e1 = t; }
      } else {
        bool amLow = (lane & j) == 0;
        bool up0 = ((i0 & k) == 0), up1 = ((i1 & k) == 0);
        unsigned long long o0 = shflx64(e0, j), o1 = shflx64(e1, j);
        e0 = (up0 == amLow) ? (e0 < o0 ? e0 : o0) : (e0 > o0 ? e0 : o0);
        e1 = (up1 == amLow) ? (e1 < o1 ? e1 : o1) : (e1 > o1 ? e1 : o1);
      }
    }
  }

  // write rows for sorted ranks i0, i1 (tail rows stay zero from prep)
#pragma unroll
  for (int s = 0; s < 2; ++s) {
    int r = s ? i1 : i0;
    unsigned long long kv = s ? e1 : e0;
    if (r < K) {
      unsigned meta = (unsigned)kv;
      int idx = (meta >> 7) & (NBOX - 1);
      int lb = meta & 127;
      const float* rr = det + (ibase + idx) * ROWF;        // original (non-offset) boxes
      float* orow = out + (ibase + r) * 6;
      orow[0] = rr[0]; orow[1] = rr[1]; orow[2] = rr[2]; orow[3] = rr[3];
      orow[4] = __uint_as_float(~(unsigned)(kv >> 32));
      orow[5] = cp_ws[ibase + idx];
      out[(size_t)BATCH * NBOX * 6 + ibase + r] = (float)lb;
      out[(size_t)BATCH * NBOX * 7 + ibase + r] = 1.0f;
    }
  }
}

extern "C" void kernel_launch(void* const* d_in, const int* in_sizes, int n_in,
                              void* d_out, int out_size, void* d_ws, size_t ws_size,
                              hipStream_t stream) {
  const float* det = (const float*)d_in[0];
  float* out = (float*)d_out;
  char* ws = (char*)d_ws;

  unsigned long long* keptb = (unsigned long long*)(ws + WS_KEPT);
  float* s_ws = (float*)(ws + WS_S);
  float* cp_ws = (float*)(ws + WS_CP);
  unsigned short* bucket = (unsigned short*)(ws + WS_BUCK);
  int* cnt = (int*)(ws + WS_CNT);
  int* kcnt = (int*)(ws + WS_KCNT);

  zclr_kernel<<<1, 512, 0, stream>>>(cnt);   // cnt and kcnt are contiguous: NCTR ints
  prep_kernel<<<BATCH * NBOX / 16, 256, 0, stream>>>(det, s_ws, cp_ws, bucket, cnt, out);
  nmsb_kernel<<<BATCH * NCLS, 64, 0, stream>>>(det, s_ws, bucket, cnt, keptb, kcnt);
  outs_kernel<<<BATCH, 1024, 0, stream>>>(det, cp_ws, keptb, kcnt, out);
}